// Round 4
// baseline (103.983 us; speedup 1.0000x reference)
//
#include <hip/hip_runtime.h>
#include <math.h>

#define PH 7
#define PW 7
#define B_ 4
#define C_ 256
#define H_ 50
#define W_ 50
#define R_ 256
#define S_ (H_ * W_)     // 2500
#define NCELL (PH * PW)  // 49
#define MAXW 9           // max window width: ceil(50/7)+1

// ---------- kernel 1: transpose (B,C,H,W)->(B,H,W,C), + roi bucketing ------
// blockIdx.z==4 is one extra slice: block (0,0,4) builds the roi->slot
// permutation that pins each batch's rois to one XCD pair (see K2 comment).
// Slot s (s%8==x) is processed on XCD x; batch b owns XCDs {2b,2b+1}.
// dec[slot*8] = {orig_idx, b, x1, y1, x2, y2, -, -}.
__global__ void transpose_chw_hwc(const float* __restrict__ in, float* __restrict__ out,
                                  const int* __restrict__ rois, int* __restrict__ dec) {
    if (blockIdx.z == 4) {
        if (blockIdx.x != 0 || blockIdx.y != 0) return;
        __shared__ int bv[R_];
        const int t = threadIdx.y * 32 + threadIdx.x;   // 0..255
        const int* roi = rois + t * 5;
        const int b  = roi[0];
        const int x1 = roi[1] >> 4;   // floor(v/16), v in [0,800)
        const int y1 = roi[2] >> 4;
        const int x2 = roi[3] >> 4;
        const int y2 = roi[4] >> 4;
        bv[t] = b;
        __syncthreads();
        // stable rank within own batch + batch totals (static-indexed counters)
        int rk = 0, c0 = 0, c1 = 0, c2 = 0, c3 = 0;
        for (int j = 0; j < R_; ++j) {
            const int bj = bv[j];                 // broadcast LDS read
            c0 += (bj == 0); c1 += (bj == 1); c2 += (bj == 2); c3 += (bj == 3);
            rk += (bj == b) & (j < t);
        }
        int slot;
        if (rk < 64) {                            // direct slot on own XCD pair
            slot = (rk >> 1) * 8 + 2 * b + (rk & 1);
        } else {                                  // overflow -> under-full slots
            int o = rk - 64;
            if (b > 0) o += max(c0 - 64, 0);
            if (b > 1) o += max(c1 - 64, 0);
            if (b > 2) o += max(c2 - 64, 0);
            const int u0 = max(64 - c0, 0), u1 = max(64 - c1, 0), u2 = max(64 - c2, 0);
            int bstar, kk;
            if (o < u0)               { bstar = 0; kk = c0 + o; }
            else if (o < u0 + u1)     { bstar = 1; kk = c1 + (o - u0); }
            else if (o < u0 + u1 + u2){ bstar = 2; kk = c2 + (o - u0 - u1); }
            else                      { bstar = 3; kk = c3 + (o - u0 - u1 - u2); }
            slot = (kk >> 1) * 8 + 2 * bstar + (kk & 1);
        }
        int* d = dec + slot * 8;
        d[0] = t; d[1] = b; d[2] = x1; d[3] = y1; d[4] = x2; d[5] = y2;
        return;
    }

    __shared__ float tile[32][33];
    const int b  = blockIdx.z;
    const int s0 = blockIdx.x * 32;
    const int c0 = blockIdx.y * 32;
    const float* inb  = in  + (size_t)b * C_ * S_;
    float*       outb = out + (size_t)b * S_ * C_;
    const int tx = threadIdx.x;
    #pragma unroll
    for (int i = threadIdx.y; i < 32; i += 8) {
        const int s = s0 + tx;
        if (s < S_) tile[i][tx] = inb[(size_t)(c0 + i) * S_ + s];
    }
    __syncthreads();
    #pragma unroll
    for (int i = threadIdx.y; i < 32; i += 8) {
        const int s = s0 + i;
        if (s < S_) outb[(size_t)s * C_ + (c0 + tx)] = tile[tx][i];
    }
}

__device__ __forceinline__ float4 max4(float4 a, float4 b) {
    a.x = fmaxf(a.x, b.x); a.y = fmaxf(a.y, b.y);
    a.z = fmaxf(a.z, b.z); a.w = fmaxf(a.w, b.w);
    return a;
}

// ---------- kernel 2: pool. One wave per (cell, slot). ----------
// bx = cell*256 + slot -> XCD = slot%8 (blockIdx round-robin). The bucketing
// pass put batch-b rois on slots with slot%8 in {2b,2b+1}, so each XCD's
// feature working set is ONE batch plane (2.56 MB) -> L2-resident, instead of
// all four (10.24 MB) -> LLC-streamed. Inner loop unchanged from round 0/3.
__global__ void __launch_bounds__(64, 4)
roi_pool_cell(const float* __restrict__ ft, const int* __restrict__ dec,
              float* __restrict__ tmp) {
    const int bx   = blockIdx.x;
    const int cell = bx >> 8;        // 0..48
    const int slot = bx & 255;       // 0..255
    const int lane = threadIdx.x;    // 0..63

    const int* d = dec + slot * 8;
    const int ridx = d[0];           // original roi index (output position)
    const int b  = d[1];
    const int x1 = d[2];
    const int y1 = d[3];
    const int x2 = d[4];
    const int y2 = d[5];
    const int h = y2 - y1 + 1;
    const int w = x2 - x1 + 1;

    const int ph = cell / PW;
    const int pw = cell - ph * PW;
    const int sh = y1 + (ph * h) / PH;
    const int eh = y1 + ((ph + 1) * h + PH - 1) / PH;
    const int sw = x1 + (pw * w) / PW;
    const int ew = x1 + ((pw + 1) * w + PW - 1) / PW;
    const int kw = ew - sw;          // 1..9, wave-uniform

    const float* fb = ft + (size_t)b * S_ * C_ + 4 * lane;

    float4 acc = make_float4(-INFINITY, -INFINITY, -INFINITY, -INFINITY);

    int y = sh;
    if ((eh - sh) & 1) {             // odd band height: single-row prologue
        const float* p0 = fb + (size_t)(y * W_ + sw) * C_;
        float4 v0[MAXW];
        #pragma unroll
        for (int k = 0; k < MAXW; ++k)
            if (k < kw) v0[k] = *(const float4*)(p0 + (size_t)k * C_);
        #pragma unroll
        for (int k = 0; k < MAXW; ++k)
            if (k < kw) acc = max4(acc, v0[k]);
        ++y;
    }
    for (; y < eh; y += 2) {         // even remainder: true row pairs
        const float* p0 = fb + (size_t)( y      * W_ + sw) * C_;
        const float* p1 = fb + (size_t)((y + 1) * W_ + sw) * C_;
        float4 v0[MAXW], v1[MAXW];
        #pragma unroll
        for (int k = 0; k < MAXW; ++k) {
            if (k < kw) {                            // wave-uniform branch
                v0[k] = *(const float4*)(p0 + (size_t)k * C_);
                v1[k] = *(const float4*)(p1 + (size_t)k * C_);
            }
        }
        #pragma unroll
        for (int k = 0; k < MAXW; ++k) {
            if (k < kw) acc = max4(acc, max4(v0[k], v1[k]));
        }
    }

    *(float4*)(tmp + ((size_t)(ridx * NCELL + cell)) * C_ + 4 * lane) = acc;
}

// ---------- kernel 3: tmp (R,49,C) -> out (R,C,49) ----------
__global__ void __launch_bounds__(256)
transpose_out(const float* __restrict__ tmp, float* __restrict__ out) {
    __shared__ float lds[NCELL * 129];  // 25.3 KB
    const int r    = blockIdx.x >> 1;
    const int c0   = (blockIdx.x & 1) << 7;   // 0 or 128
    const int t    = threadIdx.x;
    const float* src = tmp + (size_t)r * NCELL * C_ + c0;
    float*       dst = out + (size_t)r * C_ * NCELL + (size_t)c0 * NCELL;

    #pragma unroll
    for (int i = t; i < NCELL * 128; i += 256) {
        const int cell = i >> 7;         // i = cell*128 + c
        const int c    = i & 127;
        lds[cell * 129 + c] = src[(size_t)cell * C_ + c];
    }
    __syncthreads();
    #pragma unroll
    for (int f = t; f < 128 * NCELL; f += 256) {
        const int c    = f / NCELL;      // const divisor -> magic mul
        const int cell = f - c * NCELL;  // f = c*49 + cell
        dst[f] = lds[cell * 129 + c];
    }
}

extern "C" void kernel_launch(void* const* d_in, const int* in_sizes, int n_in,
                              void* d_out, int out_size, void* d_ws, size_t ws_size,
                              hipStream_t stream) {
    const float* features = (const float*)d_in[0];
    const int*   rois     = (const int*)d_in[1];
    float*       out      = (float*)d_out;

    float* ft  = (float*)d_ws;                       // 10.24 MB
    float* tmp = ft + (size_t)B_ * S_ * C_;          // +12.85 MB
    int*   dec = (int*)(tmp + (size_t)R_ * NCELL * C_);  // +8 KB (ws is 256 MB)

    dim3 tgrid((S_ + 31) / 32, C_ / 32, 5);          // z==4: bucketing slice
    transpose_chw_hwc<<<tgrid, dim3(32, 8), 0, stream>>>(features, ft, rois, dec);
    roi_pool_cell<<<NCELL * R_, 64, 0, stream>>>(ft, dec, tmp);
    transpose_out<<<R_ * 2, 256, 0, stream>>>(tmp, out);
}